// Round 4
// baseline (28203.796 us; speedup 1.0000x reference)
//
#include <hip/hip_runtime.h>
#include <stdint.h>

#define B_    64
#define H_    1024
#define E_    1024
#define V_    32000
#define SIN_  128
#define STRG_ 33
#define TDEC_ 32

__device__ __forceinline__ float sigmoidf_(float x) { return 1.f / (1.f + expf(-x)); }

// Stage 64 rows x 64 k-values of x (optionally gathered rows) into LDS.
// Layout xs[row][k], row stride 68 floats (272B: 16B-aligned rows, and the
// 64-lane float4 read pattern hits the 8-bank-cycle minimum -> conflict-free).
__device__ __forceinline__ void stage_rows(float (*xs)[68], const float* __restrict__ base,
                                           const int* __restrict__ idx, int idx_stride, int t_off,
                                           int k0, int tid)
{
    for (int j = tid; j < 1024; j += 256) {           // 1024 float4s = 64x64 floats
        int row = j >> 4, c4 = (j & 15) << 2;
        const float* xr = idx ? (base + (size_t)idx[row * idx_stride + t_off] * 1024)
                              : (base + (size_t)row * 1024);
        *(float4*)(&xs[row][c4]) = *(const float4*)(xr + k0 + c4);
    }
}

// One GRU cell output unit-group: wave `wave` of logical block `ublock` owns
// hidden unit u = ublock*4+wave across all 64 batch rows (lane = b).
// Weight addresses are wave-uniform (readfirstlane on u) -> scalar loads.
__device__ __forceinline__ void gru_unit(float (*xs)[68], int tid,
    const float* __restrict__ xbase, const int* __restrict__ idx, int idx_stride, int t_off,
    const float* __restrict__ h_old,
    const float* __restrict__ Wih, const float* __restrict__ Whh,
    const float* __restrict__ bih, const float* __restrict__ bhh,
    float* __restrict__ h_new, int ublock)
{
    const int lane = tid & 63;
    const int wave = tid >> 6;
    const int u    = __builtin_amdgcn_readfirstlane(ublock * 4 + wave);
    const int b    = lane;

    float a_r = 0.f, a_z = 0.f, a_in = 0.f, a_hn = 0.f;

    // ---- phase 0: gi = x @ Wih.T (rows u, 1024+u, 2048+u)
    for (int k0 = 0; k0 < 1024; k0 += 64) {
        __syncthreads();
        stage_rows(xs, xbase, idx, idx_stride, t_off, k0, tid);
        __syncthreads();
        const float* Wr = Wih + (size_t)u * 1024 + k0;
        const float* Wz = Wr + (size_t)1024 * 1024;
        const float* Wn = Wz + (size_t)1024 * 1024;
        #pragma unroll 8
        for (int k = 0; k < 64; k += 4) {
            float4 xv = *(const float4*)(&xs[b][k]);
            a_r  += xv.x * Wr[k] + xv.y * Wr[k+1] + xv.z * Wr[k+2] + xv.w * Wr[k+3];
            a_z  += xv.x * Wz[k] + xv.y * Wz[k+1] + xv.z * Wz[k+2] + xv.w * Wz[k+3];
            a_in += xv.x * Wn[k] + xv.y * Wn[k+1] + xv.z * Wn[k+2] + xv.w * Wn[k+3];
        }
    }
    // ---- phase 1: gh = h @ Whh.T
    for (int k0 = 0; k0 < 1024; k0 += 64) {
        __syncthreads();
        stage_rows(xs, h_old, nullptr, 0, 0, k0, tid);
        __syncthreads();
        const float* Wr = Whh + (size_t)u * 1024 + k0;
        const float* Wz = Wr + (size_t)1024 * 1024;
        const float* Wn = Wz + (size_t)1024 * 1024;
        #pragma unroll 8
        for (int k = 0; k < 64; k += 4) {
            float4 hv = *(const float4*)(&xs[b][k]);
            a_r  += hv.x * Wr[k] + hv.y * Wr[k+1] + hv.z * Wr[k+2] + hv.w * Wr[k+3];
            a_z  += hv.x * Wz[k] + hv.y * Wz[k+1] + hv.z * Wz[k+2] + hv.w * Wz[k+3];
            a_hn += hv.x * Wn[k] + hv.y * Wn[k+1] + hv.z * Wn[k+2] + hv.w * Wn[k+3];
        }
    }

    // PyTorch gate order r,z,n
    float r  = sigmoidf_(a_r + bih[u] + bhh[u]);
    float z  = sigmoidf_(a_z + bih[1024 + u] + bhh[1024 + u]);
    float n  = tanhf(a_in + bih[2048 + u] + r * (a_hn + bhh[2048 + u]));
    float ho = h_old[(size_t)b * 1024 + u];
    h_new[(size_t)b * 1024 + u] = (1.f - z) * n + z * ho;
}

// Skewed encoder step: blocks 0..255 compute layer-1 step k (x = emb[seq_in[:,k]]),
// blocks 256..511 compute layer-2 step k-1 (x = h1[k-1] -- the buffer part A READS,
// not the one it writes, so no intra-kernel dependency).
__global__ __launch_bounds__(256) void enc_fused_kernel(
    const float* __restrict__ emb, const int* __restrict__ seq_in, int t, int do_a, int do_b,
    const float* __restrict__ h1_old, float* __restrict__ h1_new,
    const float* __restrict__ h2_old, float* __restrict__ h2_new,
    const float* __restrict__ Wih1, const float* __restrict__ Whh1,
    const float* __restrict__ bih1, const float* __restrict__ bhh1,
    const float* __restrict__ Wih2, const float* __restrict__ Whh2,
    const float* __restrict__ bih2, const float* __restrict__ bhh2)
{
    __shared__ __align__(16) float xs[64][68];
    int bb = blockIdx.x;
    if (bb < 256) {
        if (!do_a) return;
        gru_unit(xs, threadIdx.x, emb, seq_in, SIN_, t, h1_old,
                 Wih1, Whh1, bih1, bhh1, h1_new, bb);
    } else {
        if (!do_b) return;
        gru_unit(xs, threadIdx.x, h1_old, nullptr, 0, 0, h2_old,
                 Wih2, Whh2, bih2, bhh2, h2_new, bb - 256);
    }
}

// Standalone GRU layer step (decoder). GATHER: x = xsrc[idx[b]] (token embedding).
template<bool GATHER>
__global__ __launch_bounds__(256) void gru_step_kernel(
    const float* __restrict__ xsrc, const int* __restrict__ idx,
    const float* __restrict__ h_old,
    const float* __restrict__ Wih, const float* __restrict__ Whh,
    const float* __restrict__ bih, const float* __restrict__ bhh,
    float* __restrict__ h_new)
{
    __shared__ __align__(16) float xs[64][68];
    gru_unit(xs, threadIdx.x, xsrc, GATHER ? idx : nullptr, 1, 0, h_old,
             Wih, Whh, bih, bhh, h_new, blockIdx.x);
}

// logits = h2 @ fc_w.T  [64][32000]. 500 blocks; wave owns 16 vocab rows; lane = b.
__global__ __launch_bounds__(256) void logits_kernel(
    const float* __restrict__ x, const float* __restrict__ fcw, float* __restrict__ logits)
{
    __shared__ __align__(16) float xs[64][68];
    const int tid = threadIdx.x, lane = tid & 63, wave = tid >> 6, b = lane;
    const int v0  = __builtin_amdgcn_readfirstlane((int)blockIdx.x * 64 + wave * 16);

    float acc[16];
    #pragma unroll
    for (int i = 0; i < 16; ++i) acc[i] = 0.f;

    for (int k0 = 0; k0 < 1024; k0 += 64) {
        __syncthreads();
        stage_rows(xs, x, nullptr, 0, 0, k0, tid);
        __syncthreads();
        const float* W0 = fcw + (size_t)v0 * 1024 + k0;
        #pragma unroll 4
        for (int k = 0; k < 64; k += 4) {
            float4 xv = *(const float4*)(&xs[b][k]);
            #pragma unroll
            for (int vi = 0; vi < 16; ++vi) {
                const float* w = W0 + (size_t)vi * 1024 + k;
                acc[vi] += xv.x * w[0] + xv.y * w[1] + xv.z * w[2] + xv.w * w[3];
            }
        }
    }

    __syncthreads();
    #pragma unroll
    for (int vi = 0; vi < 16; ++vi)
        xs[wave * 16 + vi][b] = acc[vi];           // lanes=consecutive b: depth 2 -> free
    __syncthreads();
    for (int i = tid; i < 4096; i += 256) {
        int bb = i >> 6, vv = i & 63;              // lanes -> consecutive vv: coalesced store
        logits[(size_t)bb * V_ + (size_t)blockIdx.x * 64 + vv] = xs[vv][bb];
    }
}

// Per-batch-row online softmax + argmax (first-index tie-break) + CE + next token.
__global__ __launch_bounds__(256) void reduce_kernel(
    const float* __restrict__ logits, const int* __restrict__ seq_trg,
    const int* __restrict__ force, int t,
    float* __restrict__ out, int* __restrict__ tok)
{
    __shared__ float sm[256], ss[256];
    __shared__ int   sa[256];
    const int tid = threadIdx.x;
    const int b   = blockIdx.x;
    const float* row = logits + (size_t)b * V_;

    float m = -INFINITY, s = 0.f;
    int am = 0;
    for (int i = tid; i < V_ / 4; i += 256) {
        float4 v4 = *(const float4*)(row + 4 * i);
        float vals[4] = { v4.x, v4.y, v4.z, v4.w };
        #pragma unroll
        for (int j = 0; j < 4; ++j) {
            float v = vals[j];
            if (v > m) { s = s * expf(m - v) + 1.f; m = v; am = 4 * i + j; }
            else       { s += expf(v - m); }
        }
    }
    sm[tid] = m; ss[tid] = s; sa[tid] = am;
    __syncthreads();
    for (int off = 128; off > 0; off >>= 1) {
        if (tid < off) {
            float m1 = sm[tid],     s1 = ss[tid];       int a1 = sa[tid];
            float m2 = sm[tid+off], s2 = ss[tid+off];   int a2 = sa[tid+off];
            float M = fmaxf(m1, m2);
            ss[tid] = s1 * expf(m1 - M) + s2 * expf(m2 - M);
            sm[tid] = M;
            sa[tid] = (m2 > m1) ? a2 : ((m1 > m2) ? a1 : min(a1, a2));
        }
        __syncthreads();
    }
    if (tid == 0) {
        int gold = seq_trg[b * STRG_ + t + 1];
        float logp = row[gold] - sm[0] - logf(ss[0]);
        atomicAdd(out, -logp * (1.f / (float)B_));
        int top1 = sa[0];
        out[1 + b * STRG_ + (t + 1)] = (float)top1;
        tok[b] = (force[t] != 0) ? gold : top1;   // force_teach is int32 on device
    }
}

__global__ __launch_bounds__(256) void init_kernel(
    float* __restrict__ hbufs,                 // 4 contiguous [64][1024] buffers
    const int* __restrict__ seq_trg, float* __restrict__ out, int* __restrict__ tok)
{
    int g = blockIdx.x * 256 + threadIdx.x;    // grid 256 -> 65536 threads
    for (int i = g; i < 4 * B_ * H_; i += B_ * H_) hbufs[i] = 0.f;
    if (blockIdx.x == 0) {
        if (threadIdx.x < B_) {
            int t0 = seq_trg[threadIdx.x * STRG_];
            tok[threadIdx.x] = t0;
            out[1 + threadIdx.x * STRG_] = (float)t0;   // result[:,0] = seq_trg[:,0]
        }
        if (threadIdx.x == B_) out[0] = 0.f;            // loss accumulator
    }
}

extern "C" void kernel_launch(void* const* d_in, const int* in_sizes, int n_in,
                              void* d_out, int out_size, void* d_ws, size_t ws_size,
                              hipStream_t stream)
{
    const int*     seq_in    = (const int*)d_in[0];
    const int*     seq_trg   = (const int*)d_in[1];
    const int*     force     = (const int*)d_in[2];   // bool -> int32 on device
    const float*   emb_in_w  = (const float*)d_in[3];
    const float*   enc_Wih   = (const float*)d_in[4];
    const float*   enc_Whh   = (const float*)d_in[5];
    const float*   enc_bih   = (const float*)d_in[6];
    const float*   enc_bhh   = (const float*)d_in[7];
    const float*   emb_out_w = (const float*)d_in[8];
    const float*   dec_Wih   = (const float*)d_in[9];
    const float*   dec_Whh   = (const float*)d_in[10];
    const float*   dec_bih   = (const float*)d_in[11];
    const float*   dec_bhh   = (const float*)d_in[12];
    const float*   fc_w      = (const float*)d_in[13];
    float* out = (float*)d_out;

    float* ws = (float*)d_ws;
    float* buf1[2] = { ws,               ws + B_ * H_ };
    float* buf2[2] = { ws + 2 * B_ * H_, ws + 3 * B_ * H_ };
    float* logits  = ws + 4 * B_ * H_;
    int*   tok     = (int*)(logits + (size_t)B_ * V_);

    init_kernel<<<256, 256, 0, stream>>>(ws, seq_trg, out, tok);

    const size_t WOFF = (size_t)3 * H_ * H_;
    const size_t BOFF = (size_t)3 * H_;

    // ---- encoder: 129 skewed fused launches.
    // Kernel k: part A -> h1[k] (reads buf1[(k+1)&1], writes buf1[k&1]);
    //           part B -> h2[k-1] (x = buf1[(k+1)&1] = h1[k-1],
    //                     reads buf2[(k+1)&1] = h2[k-2], writes buf2[k&1]).
    for (int k = 0; k <= SIN_; ++k) {
        const float* h1o = buf1[(k + 1) & 1];
        float*       h1n = buf1[k & 1];
        const float* h2o = buf2[(k + 1) & 1];
        float*       h2n = buf2[k & 1];
        enc_fused_kernel<<<512, 256, 0, stream>>>(
            emb_in_w, seq_in, k, (int)(k < SIN_), (int)(k >= 1),
            h1o, h1n, h2o, h2n,
            enc_Wih, enc_Whh, enc_bih, enc_bhh,
            enc_Wih + WOFF, enc_Whh + WOFF, enc_bih + BOFF, enc_bhh + BOFF);
    }
    // final states: h1[127] in buf1[1], h2[127] in buf2[0]

    // ---- decoder: 32 strictly sequential steps
    for (int t = 0; t < TDEC_; ++t) {
        const float* h1o = buf1[(t + 1) & 1];   // t=0 -> buf1[1] ✓
        float*       h1n = buf1[t & 1];
        const float* h2o = buf2[t & 1];         // t=0 -> buf2[0] ✓
        float*       h2n = buf2[(t + 1) & 1];
        gru_step_kernel<true><<<256, 256, 0, stream>>>(
            emb_out_w, tok, h1o, dec_Wih, dec_Whh, dec_bih, dec_bhh, h1n);
        gru_step_kernel<false><<<256, 256, 0, stream>>>(
            h1n, nullptr, h2o,
            dec_Wih + WOFF, dec_Whh + WOFF, dec_bih + BOFF, dec_bhh + BOFF, h2n);
        logits_kernel<<<500, 256, 0, stream>>>(h2n, fc_w, logits);
        reduce_kernel<<<64, 256, 0, stream>>>(logits, seq_trg, force, t, out, tok);
    }
}